// Round 2
// baseline (86.784 us; speedup 1.0000x reference)
//
#include <hip/hip_runtime.h>

// One-sided Chamfer: for each x_i (N=16384), min_j ||y_j - x_i||^2 over M=16384 y.
// t_ij = ||y_j||^2 - 2 x_i.y_j  (per-y precomputed as float4(-2y0,-2y1,-2y2,||y||^2))
// dist2_i = ||x_i||^2 + min_j t_ij
//
// R2 changes vs R1 (84.1us):
//  - R1 halved occupancy (512 blocks = 2 waves/SIMD) and the LDS-wait bubbles ate
//    the min3 gain. Keep XPT=8 + min3 pairing (3.5 VALU ops/pair, LDS demand
//    1 b128/14cyc < 1/12cyc capacity) but restore 4 waves/SIMD via S=64->128
//    (ychunk=128, grid 8x128=1024 blocks = 4 blocks/CU = 16 waves/CU).
//  - Right-size LDS: static sy[2048]=32KB capped residency at 5 blocks/CU;
//    sy[512]=8KB never binds (160/8=20 blocks/CU).

constexpr int TPB = 256;         // threads per block
constexpr int XPT = 8;           // x points per thread
constexpr int MAX_YCHUNK = 512;  // LDS: 512 * 16B = 8KB

__global__ __launch_bounds__(TPB) void chamfer_main(
    const float* __restrict__ x, const float* __restrict__ y,
    float* __restrict__ part, float* __restrict__ out,
    int N, int M, int ychunk) {
  __shared__ float4 sy[MAX_YCHUNK];
  const int t = threadIdx.x;
  const int bx = blockIdx.x;       // x block (TPB*XPT x-points)
  const int s = blockIdx.y;        // y chunk index

  // Init out[0] for reduce's atomicAdd (main finishes before reduce starts).
  if (bx == 0 && s == 0 && t == 0) out[0] = 0.0f;

  // Stage + transform this block's y chunk into LDS (pad to even count).
  const int ycap = (ychunk + 1) & ~1;
  for (int jj = t; jj < ycap; jj += TPB) {
    const int j = s * ychunk + jj;
    if (jj < ychunk && j < M) {
      const float y0 = y[3 * j], y1 = y[3 * j + 1], y2 = y[3 * j + 2];
      sy[jj] = make_float4(-2.0f * y0, -2.0f * y1, -2.0f * y2,
                           fmaf(y0, y0, fmaf(y1, y1, y2 * y2)));
    } else {
      sy[jj] = make_float4(0.0f, 0.0f, 0.0f, __builtin_inff());
    }
  }
  __syncthreads();

  float x0[XPT], x1[XPT], x2[XPT], mn[XPT];
#pragma unroll
  for (int k = 0; k < XPT; k++) {
    const int i = bx * (TPB * XPT) + k * TPB + t;
    const int ic = (i < N) ? i : 0;
    x0[k] = x[3 * ic];
    x1[k] = x[3 * ic + 1];
    x2[k] = x[3 * ic + 2];
    mn[k] = __builtin_inff();
  }

  // 2 y-points per iteration: 6 FMA + 1 min3 per k. Wave-uniform LDS address
  // -> broadcast, conflict-free; 2 ds_read_b128 per 112 issue-cycles per wave.
#pragma unroll 4
  for (int jj = 0; jj < ycap; jj += 2) {
    const float4 qa = sy[jj];
    const float4 qb = sy[jj + 1];
#pragma unroll
    for (int k = 0; k < XPT; k++) {
      const float ta = fmaf(x0[k], qa.x, fmaf(x1[k], qa.y, fmaf(x2[k], qa.z, qa.w)));
      const float tb = fmaf(x0[k], qb.x, fmaf(x1[k], qb.y, fmaf(x2[k], qb.z, qb.w)));
      mn[k] = fminf(mn[k], fminf(ta, tb));   // -> v_min3_f32
    }
  }

#pragma unroll
  for (int k = 0; k < XPT; k++) {
    const int i = bx * (TPB * XPT) + k * TPB + t;
    if (i < N) part[(size_t)s * N + i] = mn[k];
  }
}

__global__ __launch_bounds__(TPB) void chamfer_reduce(
    const float* __restrict__ x, const float* __restrict__ part,
    float* __restrict__ out, int N, int S) {
  const int t = threadIdx.x;
  const int i = blockIdx.x * TPB + t;

  float d = 0.0f;
  if (i < N) {
    float m = __builtin_inff();
#pragma unroll 8
    for (int s = 0; s < S; s++) m = fminf(m, part[(size_t)s * N + i]);
    const float a = x[3 * i], b = x[3 * i + 1], c = x[3 * i + 2];
    d = fmaf(a, a, fmaf(b, b, c * c)) + m;
    out[1 + i] = d;
  }

  // Block sum: wave shuffle reduce, cross-wave via LDS, one atomicAdd per block.
  float v = d;
#pragma unroll
  for (int off = 32; off > 0; off >>= 1) v += __shfl_down(v, off, 64);
  __shared__ float wsum[TPB / 64];
  if ((t & 63) == 0) wsum[t >> 6] = v;
  __syncthreads();
  if (t == 0) {
    float ssum = 0.0f;
#pragma unroll
    for (int w = 0; w < TPB / 64; w++) ssum += wsum[w];
    atomicAdd(out, ssum);
  }
}

extern "C" void kernel_launch(void* const* d_in, const int* in_sizes, int n_in,
                              void* d_out, int out_size, void* d_ws, size_t ws_size,
                              hipStream_t stream) {
  const float* x = (const float*)d_in[0];
  const float* y = (const float*)d_in[1];
  float* out = (float*)d_out;

  const int N = in_sizes[0] / 3;  // 16384
  const int M = in_sizes[1] / 3;  // 16384

  // S=128 -> ychunk=128, grid 1024 blocks (4/CU, 16 waves/CU = 4/SIMD).
  int S = 128;
  while (S > 8 && (size_t)S * N * sizeof(float) > ws_size) S >>= 1;
  int ychunk = (M + S - 1) / S;
  while (ychunk > MAX_YCHUNK) { S <<= 1; ychunk = (M + S - 1) / S; }

  float* part = (float*)d_ws;  // [S][N]

  const int xblocks = (N + TPB * XPT - 1) / (TPB * XPT);  // 8
  dim3 gridB(xblocks, S);                                  // 1024 blocks
  chamfer_main<<<gridB, TPB, 0, stream>>>(x, y, part, out, N, M, ychunk);

  const int rblocks = (N + TPB - 1) / TPB;  // 64
  chamfer_reduce<<<rblocks, TPB, 0, stream>>>(x, part, out, N, S);
}

// Round 3
// 82.351 us; speedup vs baseline: 1.0538x; 1.0538x over previous
//
#include <hip/hip_runtime.h>

// One-sided Chamfer: for each x_i (N=16384), min_j ||y_j - x_i||^2 over M=16384 y.
// t_ij = ||y_j||^2 - 2 x_i.y_j  (per-y precomputed as float4(-2y0,-2y1,-2y2,||y||^2))
// dist2_i = ||x_i||^2 + min_j t_ij
//
// R3: kill the part[] pipeline. R0-R2 showed main is near its VALU floor and the
// S-chunk partials cost real time (R2: S=128 doubled reduce's strided read -> +2.6us).
//  - main now merges chunk minima via atomicMin on float-as-uint (d >= 0, so IEEE
//    order == integer order). No workspace at all.
//  - init kernel sets out[0]=0, out[1+i]=+inf (atomicMin identity).
//  - sum kernel reads final out[1+i], block-reduces, one atomicAdd per block
//    (same summation structure as R1/R2, passed at absmax 2.4e-4).

constexpr int TPB = 256;         // threads per block
constexpr int XPT = 8;           // x points per thread
constexpr int MAX_YCHUNK = 512;  // LDS: 512 * 16B = 8KB

__global__ __launch_bounds__(TPB) void chamfer_init(float* __restrict__ out, int N) {
  const int i = blockIdx.x * TPB + threadIdx.x;
  if (i == 0) out[0] = 0.0f;
  if (i < N) out[1 + i] = __builtin_inff();
}

__global__ __launch_bounds__(TPB) void chamfer_main(
    const float* __restrict__ x, const float* __restrict__ y,
    float* __restrict__ out, int N, int M, int ychunk) {
  __shared__ float4 sy[MAX_YCHUNK];
  const int t = threadIdx.x;
  const int bx = blockIdx.x;       // x block (TPB*XPT x-points)
  const int s = blockIdx.y;        // y chunk index

  // Stage + transform this block's y chunk into LDS (pad to even count).
  const int ycap = (ychunk + 1) & ~1;
  for (int jj = t; jj < ycap; jj += TPB) {
    const int j = s * ychunk + jj;
    if (jj < ychunk && j < M) {
      const float y0 = y[3 * j], y1 = y[3 * j + 1], y2 = y[3 * j + 2];
      sy[jj] = make_float4(-2.0f * y0, -2.0f * y1, -2.0f * y2,
                           fmaf(y0, y0, fmaf(y1, y1, y2 * y2)));
    } else {
      sy[jj] = make_float4(0.0f, 0.0f, 0.0f, __builtin_inff());
    }
  }
  __syncthreads();

  float x0[XPT], x1[XPT], x2[XPT], mn[XPT];
#pragma unroll
  for (int k = 0; k < XPT; k++) {
    const int i = bx * (TPB * XPT) + k * TPB + t;
    const int ic = (i < N) ? i : 0;
    x0[k] = x[3 * ic];
    x1[k] = x[3 * ic + 1];
    x2[k] = x[3 * ic + 2];
    mn[k] = __builtin_inff();
  }

  // 2 y-points per iteration: 6 FMA + 1 min3 per k. Wave-uniform LDS address
  // -> broadcast, conflict-free.
#pragma unroll 4
  for (int jj = 0; jj < ycap; jj += 2) {
    const float4 qa = sy[jj];
    const float4 qb = sy[jj + 1];
#pragma unroll
    for (int k = 0; k < XPT; k++) {
      const float ta = fmaf(x0[k], qa.x, fmaf(x1[k], qa.y, fmaf(x2[k], qa.z, qa.w)));
      const float tb = fmaf(x0[k], qb.x, fmaf(x1[k], qb.y, fmaf(x2[k], qb.z, qb.w)));
      mn[k] = fminf(mn[k], fminf(ta, tb));   // -> v_min3_f32
    }
  }

  // d = ||x||^2 + min_chunk t  >= 0, so uint compare == float compare.
  unsigned int* uo = (unsigned int*)(out + 1);
#pragma unroll
  for (int k = 0; k < XPT; k++) {
    const int i = bx * (TPB * XPT) + k * TPB + t;
    if (i < N) {
      const float d = fmaf(x0[k], x0[k], fmaf(x1[k], x1[k], x2[k] * x2[k])) + mn[k];
      atomicMin(&uo[i], __float_as_uint(d));
    }
  }
}

__global__ __launch_bounds__(TPB) void chamfer_sum(
    float* __restrict__ out, int N) {
  const int t = threadIdx.x;
  const int i = blockIdx.x * TPB + t;

  float v = (i < N) ? out[1 + i] : 0.0f;
#pragma unroll
  for (int off = 32; off > 0; off >>= 1) v += __shfl_down(v, off, 64);
  __shared__ float wsum[TPB / 64];
  if ((t & 63) == 0) wsum[t >> 6] = v;
  __syncthreads();
  if (t == 0) {
    float ssum = 0.0f;
#pragma unroll
    for (int w = 0; w < TPB / 64; w++) ssum += wsum[w];
    atomicAdd(out, ssum);
  }
}

extern "C" void kernel_launch(void* const* d_in, const int* in_sizes, int n_in,
                              void* d_out, int out_size, void* d_ws, size_t ws_size,
                              hipStream_t stream) {
  const float* x = (const float*)d_in[0];
  const float* y = (const float*)d_in[1];
  float* out = (float*)d_out;

  const int N = in_sizes[0] / 3;  // 16384
  const int M = in_sizes[1] / 3;  // 16384

  // S=128 -> ychunk=128, grid 8x128=1024 blocks (4/CU, 16 waves/CU).
  int S = 128;
  int ychunk = (M + S - 1) / S;
  while (ychunk > MAX_YCHUNK) { S <<= 1; ychunk = (M + S - 1) / S; }

  const int iblocks = (N + TPB - 1) / TPB;  // 64
  chamfer_init<<<iblocks, TPB, 0, stream>>>(out, N);

  const int xblocks = (N + TPB * XPT - 1) / (TPB * XPT);  // 8
  dim3 gridB(xblocks, S);                                  // 1024 blocks
  chamfer_main<<<gridB, TPB, 0, stream>>>(x, y, out, N, M, ychunk);

  chamfer_sum<<<iblocks, TPB, 0, stream>>>(out, N);
}